// Round 11
// baseline (306.603 us; speedup 1.0000x reference)
//
#include <hip/hip_runtime.h>
#include <math.h>

typedef __attribute__((ext_vector_type(8))) short bf16x8;   // 8 bf16 = 4 VGPRs
typedef __attribute__((ext_vector_type(4))) float floatx4;

static __device__ __forceinline__ short f2bf(float f) {
    union { float f; unsigned u; } a; a.f = f;
    unsigned r = a.u + 0x7fffu + ((a.u >> 16) & 1u);   // RNE
    return (short)(r >> 16);
}
static __device__ __forceinline__ float bf2f(short s) {
    union { unsigned u; float f; } c; c.u = ((unsigned)(unsigned short)s) << 16;
    return c.f;
}

// ---------------------------------------------------------------------------
// prep: 16 blocks; block bb:
//   - computes qwk rows [bb*16, bb*16+16) and packs them straight into Bq
//   - packs Wv / Wo rows [bb*16, bb*16+16) into Wvh / Bo (coalesced reads)
// ---------------------------------------------------------------------------
__global__ __launch_bounds__(256) void prep_kernel(
    const float* __restrict__ query,        // [2][256]
    const float* __restrict__ Wk,           // [256][256]
    const float* __restrict__ rpe_bias,     // [9][16]
    const float* __restrict__ attn_scale_w, // [9][16]
    const float* __restrict__ Wv,           // [256][256]
    const float* __restrict__ Wo,           // [256][256]
    float* __restrict__ rpe_exp,            // out [9][16]
    float* __restrict__ rpe_scale,          // out [9][16]
    short* __restrict__ Bq,                 // out [4096]  (MFMA b-frag layout)
    short* __restrict__ Wvh,                // out [65536] (full b-frag pack)
    short* __restrict__ Bo)                 // out [65536]
{
    __shared__ float qn[16 * 33];
    __shared__ float Wt[16][260];
    __shared__ float qwk_s[16][17];
    int tid = threadIdx.x, bb = blockIdx.x;

    for (int i = tid; i < 512; i += 256) {
        int qq  = i >> 8;
        int rem = i & 255;
        int h   = rem >> 5;
        int d   = rem & 31;
        qn[((qq << 3) + h) * 33 + d] = query[i];
    }
    for (int i = tid; i < 16 * 256; i += 256)
        Wt[i >> 8][i & 255] = Wk[bb * 16 * 256 + i];
    __syncthreads();
    if (tid < 16) {
        float s = 0.f;
        #pragma unroll
        for (int d = 0; d < 32; ++d) { float t = qn[tid * 33 + d]; s += t * t; }
        float inv = 1.0f / ((sqrtf(s) + 1e-6f) * sqrtf(32.0f));
        #pragma unroll
        for (int d = 0; d < 32; ++d) qn[tid * 33 + d] *= inv;
    }
    __syncthreads();

    int g  = tid & 15;
    int Dl = tid >> 4;
    int h2 = g & 7;
    float acc = 0.f;
    #pragma unroll
    for (int d = 0; d < 32; ++d)
        acc += qn[g * 33 + d] * Wt[Dl][h2 * 32 + d];
    qwk_s[Dl][g] = acc;
    __syncthreads();

    // Bq pack for this block's 16 k-rows (b-frag: id = kc*512 + lane*8 + j)
    {
        int kl = tid >> 4, gg = tid & 15;
        int k  = bb * 16 + kl;
        int kc = k >> 5, q5 = k & 31, qd = q5 >> 3, j = q5 & 7;
        int lane = qd * 16 + gg;
        Bq[kc * 512 + lane * 8 + j] = f2bf(qwk_s[kl][gg]);
    }

    // Wvh / Bo pack: coalesced row reads (thread = column n)
    for (int kl = 0; kl < 16; ++kl) {
        int k  = bb * 16 + kl;
        int kc = k >> 5, q5 = k & 31, qd = q5 >> 3, j = q5 & 7;
        int n  = tid;
        int gg = n & 15;
        int lane = qd * 16 + gg;
        float vv = Wv[k * 256 + n];
        float vo = Wo[k * 256 + n];
        int nt  = n >> 4;
        Wvh[nt * 4096 + kc * 512 + lane * 8 + j] = f2bf(vv);
        Bo[nt * 4096 + kc * 512 + lane * 8 + j]  = f2bf(vo);
    }

    if (bb == 0 && tid < 144) {
        float r = expf(rpe_bias[tid]);
        rpe_exp[tid]   = r;
        rpe_scale[tid] = r * attn_scale_w[tid];
    }
}

// ---------------------------------------------------------------------------
// Kernel A (v3): persistent software-pipelined stream.
// 512 blocks (exactly 2/CU, all resident) x 4 tiles of 64 pixels.
// Double-buffered XA (2 x 33.8 KB). Per tile: issue next tile's x loads
// into regs FIRST -> compute current tile (ces + kc-outer V-GEMM) from LDS
// while loads fly -> convert+store regs to other buffer -> ONE barrier ->
// V/ces global stores issued after the barrier (drain under next compute).
// The x stream never stops; 4 barriers/tile -> 1.
// __launch_bounds__(256,2): 256-VGPR budget, no spill of the 64 prefetch
// VGPRs; 2 blocks/CU co-residency matches the LDS footprint.
// ---------------------------------------------------------------------------
#define XROWA 264
__global__ __launch_bounds__(256, 2) void va_kernel(
    const float* __restrict__ x,          // [131072][256] fp32
    const short* __restrict__ Bq,         // [4096]
    const short* __restrict__ Wvh,        // [65536]
    short* __restrict__ V,                // out [131072][256] bf16
    float* __restrict__ cesg)             // out [131072][16] fp32
{
    __shared__ short XA[2][64 * XROWA];   // 67584 B
    int tid  = threadIdx.x;
    int lane = tid & 63, wv = tid >> 6;   // 4 waves
    int m16  = lane & 15, quad = lane >> 4;

    float4 fA[8], fB[8];                  // prefetch registers (64 VGPR)

    // prologue: load + stage tile 0
    {
        size_t pb = (size_t)blockIdx.x * 64;
        #pragma unroll
        for (int i = 0; i < 8; ++i) {
            int it = tid + i * 256, row = it >> 5, l = it & 31;
            const float* xp = x + (pb + row) * 256 + l * 8;
            fA[i] = *(const float4*)xp;
            fB[i] = *(const float4*)(xp + 4);
        }
        #pragma unroll
        for (int i = 0; i < 8; ++i) {
            int it = tid + i * 256, row = it >> 5, l = it & 31;
            bf16x8 s;
            s[0] = f2bf(fA[i].x); s[1] = f2bf(fA[i].y);
            s[2] = f2bf(fA[i].z); s[3] = f2bf(fA[i].w);
            s[4] = f2bf(fB[i].x); s[5] = f2bf(fB[i].y);
            s[6] = f2bf(fB[i].z); s[7] = f2bf(fB[i].w);
            *(bf16x8*)&XA[0][row * XROWA + l * 8] = s;
        }
    }
    __syncthreads();

    const short* bvw = Wvh + (4 * wv) * 4096 + lane * 8;
    const short* bq  = Bq + lane * 8;

    for (int t = 0; t < 4; ++t) {
        int cur = t & 1;
        size_t p0 = (size_t)(blockIdx.x + t * 512) * 64;

        // issue next tile's loads EARLY (fly under compute)
        if (t < 3) {
            size_t pn = (size_t)(blockIdx.x + (t + 1) * 512) * 64;
            #pragma unroll
            for (int i = 0; i < 8; ++i) {
                int it = tid + i * 256, row = it >> 5, l = it & 31;
                const float* xp = x + (pn + row) * 256 + l * 8;
                fA[i] = *(const float4*)xp;
                fB[i] = *(const float4*)(xp + 4);
            }
        }

        // ces = exp(X . qwk) for this wave's m-tile
        float ce[4];
        {
            floatx4 acq = (floatx4){0.f, 0.f, 0.f, 0.f};
            const short* xrow = &XA[cur][(wv * 16 + m16) * XROWA + quad * 8];
            #pragma unroll
            for (int kc = 0; kc < 8; ++kc) {
                bf16x8 a = *(const bf16x8*)(xrow + kc * 32);
                acq = __builtin_amdgcn_mfma_f32_16x16x32_bf16(
                          a, *(const bf16x8*)(bq + kc * 512), acq, 0, 0, 0);
            }
            #pragma unroll
            for (int r = 0; r < 4; ++r) ce[r] = expf(acq[r]);
        }

        // V = X . Wv : kc-outer, acc[m][local nt], all static-indexed
        floatx4 acc[4][4];
        #pragma unroll
        for (int m = 0; m < 4; ++m)
            #pragma unroll
            for (int ln = 0; ln < 4; ++ln)
                acc[m][ln] = (floatx4){0.f, 0.f, 0.f, 0.f};
        #pragma unroll
        for (int kc = 0; kc < 8; ++kc) {
            bf16x8 B0 = *(const bf16x8*)(bvw + 0 * 4096 + kc * 512);
            bf16x8 B1 = *(const bf16x8*)(bvw + 1 * 4096 + kc * 512);
            bf16x8 B2 = *(const bf16x8*)(bvw + 2 * 4096 + kc * 512);
            bf16x8 B3 = *(const bf16x8*)(bvw + 3 * 4096 + kc * 512);
            #pragma unroll
            for (int m = 0; m < 4; ++m) {
                bf16x8 a = *(const bf16x8*)
                    &XA[cur][(m * 16 + m16) * XROWA + kc * 32 + quad * 8];
                acc[m][0] = __builtin_amdgcn_mfma_f32_16x16x32_bf16(a, B0, acc[m][0], 0, 0, 0);
                acc[m][1] = __builtin_amdgcn_mfma_f32_16x16x32_bf16(a, B1, acc[m][1], 0, 0, 0);
                acc[m][2] = __builtin_amdgcn_mfma_f32_16x16x32_bf16(a, B2, acc[m][2], 0, 0, 0);
                acc[m][3] = __builtin_amdgcn_mfma_f32_16x16x32_bf16(a, B3, acc[m][3], 0, 0, 0);
            }
        }

        // stage next tile into the other buffer (waits its loads only here)
        if (t < 3) {
            #pragma unroll
            for (int i = 0; i < 8; ++i) {
                int it = tid + i * 256, row = it >> 5, l = it & 31;
                bf16x8 s;
                s[0] = f2bf(fA[i].x); s[1] = f2bf(fA[i].y);
                s[2] = f2bf(fA[i].z); s[3] = f2bf(fA[i].w);
                s[4] = f2bf(fB[i].x); s[5] = f2bf(fB[i].y);
                s[6] = f2bf(fB[i].z); s[7] = f2bf(fB[i].w);
                *(bf16x8*)&XA[cur ^ 1][row * XROWA + l * 8] = s;
            }
        }
        __syncthreads();

        // global stores AFTER the barrier: drain under next tile's compute
        #pragma unroll
        for (int r = 0; r < 4; ++r)
            cesg[(p0 + wv * 16 + quad * 4 + r) * 16 + m16] = ce[r];
        #pragma unroll
        for (int m = 0; m < 4; ++m)
            #pragma unroll
            for (int ln = 0; ln < 4; ++ln)
                #pragma unroll
                for (int r = 0; r < 4; ++r)
                    V[(p0 + m * 16 + quad * 4 + r) * 256 +
                      (4 * wv + ln) * 16 + m16] = f2bf(acc[m][ln][r]);
    }
}

// ---------------------------------------------------------------------------
// Kernel B: softmax-stencil + output projection (unchanged, verified ~25 us).
// ---------------------------------------------------------------------------
#define OROW 264
__global__ __launch_bounds__(512) void qb_kernel(
    const float* __restrict__ cesg,       // [131072][16]
    const short* __restrict__ V,          // [131072][256] bf16
    const float* __restrict__ rpe_exp,    // [9][16]
    const float* __restrict__ rpe_scale,  // [9][16]
    const short* __restrict__ Bo,         // [65536]
    float* __restrict__ out)              // [32768][256] fp32
{
    __shared__ short out_tr[16 * OROW];   // 8448 B
    __shared__ float wcoefs[8][9][16];    // 4608 B [h][w][op]
    __shared__ float invden[16][16];      // 1024 B  (total 14080)

    int tid  = threadIdx.x;
    int lane = tid & 63, wv = tid >> 6;
    int m16  = lane & 15, quad = lane >> 4;

    int blk0 = blockIdx.x;
    int blk  = ((blk0 & 7) << 8) | (blk0 >> 3);  // XCD-contiguous, bijective
    int b   = blk >> 6;
    int io  = (blk >> 1) & 31;
    int hf  = blk & 1;
    int i0  = io * 2 - 1;
    int jbase = hf * 32 - 1;

    // ---- P2a: invden ----
    if (tid < 256) {
        int op = tid >> 4, g = tid & 15;
        float den = 0.f;
        #pragma unroll
        for (int w = 0; w < 9; ++w) {
            int ky = w / 3, kx = w - ky * 3;
            int ii = i0 + ky, jj = jbase + 2 * op + kx;
            if ((unsigned)ii < 64u && (unsigned)jj < 64u) {
                size_t pix = ((size_t)((b << 6) + ii) << 6) + jj;
                den = fmaf(rpe_exp[w * 16 + g], cesg[pix * 16 + g], den);
            }
        }
        invden[op][g] = 1.0f / den;
    }
    __syncthreads();

    // ---- P2b: wcoefs[h][w][op] (queries q=0/1 merged; 0 when OOB) ----
    for (int it = tid; it < 1152; it += 512) {
        int op = it / 72, r = it - op * 72;
        int w = r >> 3, h = r & 7;
        int ky = w / 3, kx = w - ky * 3;
        int ii = i0 + ky, jj = jbase + 2 * op + kx;
        float v = 0.f;
        if ((unsigned)ii < 64u && (unsigned)jj < 64u) {
            size_t pix = ((size_t)((b << 6) + ii) << 6) + jj;
            v = cesg[pix * 16 + h]     * rpe_scale[w * 16 + h]     * invden[op][h] +
                cesg[pix * 16 + 8 + h] * rpe_scale[w * 16 + 8 + h] * invden[op][8 + h];
        }
        wcoefs[h][w][op] = v;
    }
    __syncthreads();

    // ---- P3: stencil on V (global, coalesced 512B rows) -> out_tr ----
    {
        int op = tid >> 5;                // 0..15
        int nc = tid & 31;                // 8-feature chunk
        int h  = nc >> 2;
        float wcv[9];
        #pragma unroll
        for (int w = 0; w < 9; ++w) wcv[w] = wcoefs[h][w][op];

        float o[8];
        #pragma unroll
        for (int j = 0; j < 8; ++j) o[j] = 0.f;
        #pragma unroll
        for (int w = 0; w < 9; ++w) {
            int ky = w / 3, kx = w - ky * 3;
            int ii = i0 + ky, jj = jbase + 2 * op + kx;
            bool valid = ((unsigned)ii < 64u) && ((unsigned)jj < 64u);
            size_t pix = valid ? (((size_t)((b << 6) + ii) << 6) + jj) : 0;
            bf16x8 vv = *(const bf16x8*)&V[pix * 256 + nc * 8];
            #pragma unroll
            for (int j = 0; j < 8; ++j)
                o[j] = fmaf(wcv[w], bf2f(vv[j]), o[j]);   // wcv==0 when OOB
        }
        bf16x8 ob;
        #pragma unroll
        for (int j = 0; j < 8; ++j) ob[j] = f2bf(o[j]);
        *(bf16x8*)&out_tr[op * OROW + nc * 8] = ob;
    }
    __syncthreads();

    // ---- P5: out = out_tr . Wo (nt pair = wave), write fp32 ----
    {
        floatx4 acc0 = (floatx4){0.f, 0.f, 0.f, 0.f};
        floatx4 acc1 = (floatx4){0.f, 0.f, 0.f, 0.f};
        int nt0 = wv * 2;
        const short* bp = Bo + nt0 * 4096 + lane * 8;
        #pragma unroll
        for (int kc = 0; kc < 8; ++kc) {
            bf16x8 a  = *(const bf16x8*)&out_tr[m16 * OROW + kc * 32 + quad * 8];
            bf16x8 b0 = *(const bf16x8*)(bp + kc * 512);
            bf16x8 b1 = *(const bf16x8*)(bp + 4096 + kc * 512);
            acc0 = __builtin_amdgcn_mfma_f32_16x16x32_bf16(a, b0, acc0, 0, 0, 0);
            acc1 = __builtin_amdgcn_mfma_f32_16x16x32_bf16(a, b1, acc1, 0, 0, 0);
        }
        size_t op0 = (size_t)blk * 16;
        #pragma unroll
        for (int r = 0; r < 4; ++r) {
            out[(op0 + quad * 4 + r) * 256 + nt0 * 16 + m16]       = acc0[r];
            out[(op0 + quad * 4 + r) * 256 + (nt0 + 1) * 16 + m16] = acc1[r];
        }
    }
}

// ---------------------------------------------------------------------------
// workspace layout (floats):
//   [0,144) rpe_exp  [144,288) rpe_scale  [288,2336) Bq
//   [2336,35104) Wvh  [35104,67872) Bo
//   [68608, +16777216) V (64 MiB bf16)   [+16777216, +2097152) ces (8 MiB)
// ---------------------------------------------------------------------------
extern "C" void kernel_launch(void* const* d_in, const int* in_sizes, int n_in,
                              void* d_out, int out_size, void* d_ws, size_t ws_size,
                              hipStream_t stream)
{
    const float* x     = (const float*)d_in[0];
    const float* query = (const float*)d_in[1];
    const float* Wk    = (const float*)d_in[2];
    const float* Wv    = (const float*)d_in[3];
    const float* rpe   = (const float*)d_in[4];
    const float* asw   = (const float*)d_in[5];
    const float* Wo    = (const float*)d_in[6];
    float* out = (float*)d_out;

    float* ws        = (float*)d_ws;
    float* rpe_exp   = ws;
    float* rpe_scale = ws + 144;
    short* Bq        = (short*)(ws + 288);
    short* Wvh       = (short*)(ws + 288 + 2048);
    short* Bo        = (short*)(ws + 288 + 2048 + 32768);
    short* V         = (short*)(ws + 68608);
    float* cesg      = ws + 68608 + 16777216;

    prep_kernel<<<dim3(16), dim3(256), 0, stream>>>(query, Wk, rpe, asw, Wv, Wo,
                                                    rpe_exp, rpe_scale, Bq, Wvh, Bo);
    va_kernel<<<dim3(512), dim3(256), 0, stream>>>(x, Bq, Wvh, V, cesg);
    qb_kernel<<<dim3(2048), dim3(512), 0, stream>>>(cesg, V, rpe_exp, rpe_scale,
                                                    Bo, out);
}

// Round 12
// 268.208 us; speedup vs baseline: 1.1432x; 1.1432x over previous
//
#include <hip/hip_runtime.h>
#include <math.h>

typedef __attribute__((ext_vector_type(8))) short bf16x8;   // 8 bf16 = 4 VGPRs
typedef __attribute__((ext_vector_type(4))) float floatx4;

static __device__ __forceinline__ short f2bf(float f) {
    union { float f; unsigned u; } a; a.f = f;
    unsigned r = a.u + 0x7fffu + ((a.u >> 16) & 1u);   // RNE
    return (short)(r >> 16);
}
static __device__ __forceinline__ float bf2f(short s) {
    union { unsigned u; float f; } c; c.u = ((unsigned)(unsigned short)s) << 16;
    return c.f;
}

// ---------------------------------------------------------------------------
// prep: 16 blocks; block bb:
//   - computes qwk rows [bb*16, bb*16+16) and packs them straight into Bq
//   - packs Wv / Wo rows [bb*16, bb*16+16) into Wvh / Bo (coalesced reads)
// ---------------------------------------------------------------------------
__global__ __launch_bounds__(256) void prep_kernel(
    const float* __restrict__ query,        // [2][256]
    const float* __restrict__ Wk,           // [256][256]
    const float* __restrict__ rpe_bias,     // [9][16]
    const float* __restrict__ attn_scale_w, // [9][16]
    const float* __restrict__ Wv,           // [256][256]
    const float* __restrict__ Wo,           // [256][256]
    float* __restrict__ rpe_exp,            // out [9][16]
    float* __restrict__ rpe_scale,          // out [9][16]
    short* __restrict__ Bq,                 // out [4096]  (MFMA b-frag layout)
    short* __restrict__ Wvh,                // out [65536] (full b-frag pack)
    short* __restrict__ Bo)                 // out [65536]
{
    __shared__ float qn[16 * 33];
    __shared__ float Wt[16][260];
    __shared__ float qwk_s[16][17];
    int tid = threadIdx.x, bb = blockIdx.x;

    for (int i = tid; i < 512; i += 256) {
        int qq  = i >> 8;
        int rem = i & 255;
        int h   = rem >> 5;
        int d   = rem & 31;
        qn[((qq << 3) + h) * 33 + d] = query[i];
    }
    for (int i = tid; i < 16 * 256; i += 256)
        Wt[i >> 8][i & 255] = Wk[bb * 16 * 256 + i];
    __syncthreads();
    if (tid < 16) {
        float s = 0.f;
        #pragma unroll
        for (int d = 0; d < 32; ++d) { float t = qn[tid * 33 + d]; s += t * t; }
        float inv = 1.0f / ((sqrtf(s) + 1e-6f) * sqrtf(32.0f));
        #pragma unroll
        for (int d = 0; d < 32; ++d) qn[tid * 33 + d] *= inv;
    }
    __syncthreads();

    int g  = tid & 15;
    int Dl = tid >> 4;
    int h2 = g & 7;
    float acc = 0.f;
    #pragma unroll
    for (int d = 0; d < 32; ++d)
        acc += qn[g * 33 + d] * Wt[Dl][h2 * 32 + d];
    qwk_s[Dl][g] = acc;
    __syncthreads();

    // Bq pack for this block's 16 k-rows (b-frag: id = kc*512 + lane*8 + j)
    {
        int kl = tid >> 4, gg = tid & 15;
        int k  = bb * 16 + kl;
        int kc = k >> 5, q5 = k & 31, qd = q5 >> 3, j = q5 & 7;
        int lane = qd * 16 + gg;
        Bq[kc * 512 + lane * 8 + j] = f2bf(qwk_s[kl][gg]);
    }

    // Wvh / Bo pack: coalesced row reads (thread = column n)
    for (int kl = 0; kl < 16; ++kl) {
        int k  = bb * 16 + kl;
        int kc = k >> 5, q5 = k & 31, qd = q5 >> 3, j = q5 & 7;
        int n  = tid;
        int gg = n & 15;
        int lane = qd * 16 + gg;
        float vv = Wv[k * 256 + n];
        float vo = Wo[k * 256 + n];
        int nt  = n >> 4;
        Wvh[nt * 4096 + kc * 512 + lane * 8 + j] = f2bf(vv);
        Bo[nt * 4096 + kc * 512 + lane * 8 + j]  = f2bf(vo);
    }

    if (bb == 0 && tid < 144) {
        float r = expf(rpe_bias[tid]);
        rpe_exp[tid]   = r;
        rpe_scale[tid] = r * attn_scale_w[tid];
    }
}

// ---------------------------------------------------------------------------
// fused8: monolith at 8-output-pixel granularity -> 4 blocks/CU.
// Window = 3 x 17 input px = 51 rows (padded to 64) = 33.8 KB; total LDS
// 40,832 B -> EXACTLY 4 co-resident blocks (4 x 40,960 = 160 KB), double
// the barrier-domain overlap of the 16-px monolith (which was 2/CU).
// 256 thr (4 waves). 6 barriers (was 13).
// P0:  stage window -> XA bf16 (64 rows x 256, XROW pad)
// P1:  cost MFMA -> ces (wave = m-tile)
// P1V: kc-outer V = X.Wv (wave owns 4 nt, B streams from L2, A from LDS);
//      barrier; V written in place over XA (all reads done)
// P2a/P2b: invden; wcoefs[h][w][op]   (ces=0 rows make OOB taps weight-0)
// P3:  stencil pre[op][n] = sum_w wc * V -> out_tr (aliases ces pool)
// P5:  out = out_tr . Wo (wave owns 4 nt; M padded 8->16 via m16&7 clamp,
//      duplicate rows computed but not stored)
// ---------------------------------------------------------------------------
#define XROW 264
#define CESR 19
__global__ __launch_bounds__(256, 4) void fused8_kernel(
    const float* __restrict__ x,          // [131072][256] fp32
    const float* __restrict__ rpe_exp,    // [9][16]
    const float* __restrict__ rpe_scale,  // [9][16]
    const short* __restrict__ Bq,         // [4096]
    const short* __restrict__ Wvh,        // [65536]
    const short* __restrict__ Bo,         // [65536]
    float* __restrict__ out)              // [32768][256] fp32
{
    __shared__ short XA[64 * XROW];                       // 33792 B (X, then V)
    __shared__ __align__(16) unsigned char pool[4224];    // ces | out_tr
    __shared__ float wcoefs[8][9][8];                     // 2304 B [h][w][op]
    __shared__ float invden[8][16];                       // 512 B (tot 40832)

    float* ces    = (float*)pool;     // live P1..P2b  (<=3860 B used)
    short* out_tr = (short*)pool;     // live P3..P5   (8 rows x XROW, clamped)

    int tid  = threadIdx.x;
    int lane = tid & 63, wv = tid >> 6;   // 4 waves
    int m16  = lane & 15, quad = lane >> 4;

    int blk0 = blockIdx.x;                // 4096 blocks; 4096%8==0 -> bijective
    int blk  = ((blk0 & 7) << 9) | (blk0 >> 3);
    int b   = blk >> 7;
    int io  = (blk >> 2) & 31;
    int oc  = blk & 3;
    int i0  = io * 2 - 1;
    int jbase = oc * 16 - 1;

    // ---- P0: stage 3x17 window (51 rows) + zero pad rows 51..63 ----
    #pragma unroll
    for (int i = 0; i < 8; ++i) {
        int it  = tid + i * 256;          // 0..2047 = 64 rows x 32 chunks
        int row = it >> 5;
        int l   = it & 31;
        int ky  = row / 17;
        int jloc = row - ky * 17;
        int ii = i0 + ky, jj = jbase + jloc;
        bool valid = (row < 51) && ((unsigned)ii < 64u) && ((unsigned)jj < 64u);
        bf16x8 s;
        if (valid) {
            const float* xp = x + ((size_t)(((b << 6) + ii) << 6) + jj) * 256 + l * 8;
            float4 f0 = *(const float4*)xp;
            float4 f1 = *(const float4*)(xp + 4);
            s[0] = f2bf(f0.x); s[1] = f2bf(f0.y); s[2] = f2bf(f0.z); s[3] = f2bf(f0.w);
            s[4] = f2bf(f1.x); s[5] = f2bf(f1.y); s[6] = f2bf(f1.z); s[7] = f2bf(f1.w);
        } else {
            #pragma unroll
            for (int j = 0; j < 8; ++j) s[j] = 0;
        }
        *(bf16x8*)&XA[row * XROW + l * 8] = s;
    }
    __syncthreads();

    // ---- P1: cost MFMA -> ces (wave = m-tile wv) ----
    {
        floatx4 accc = (floatx4){0.f, 0.f, 0.f, 0.f};
        const short* bq   = Bq + lane * 8;
        const short* xrow = &XA[(wv * 16 + m16) * XROW + quad * 8];
        #pragma unroll
        for (int kc = 0; kc < 8; ++kc) {
            bf16x8 a = *(const bf16x8*)(xrow + kc * 32);
            accc = __builtin_amdgcn_mfma_f32_16x16x32_bf16(
                       a, *(const bf16x8*)(bq + kc * 512), accc, 0, 0, 0);
        }
        #pragma unroll
        for (int r = 0; r < 4; ++r) {
            int p = wv * 16 + quad * 4 + r;
            int ky = p / 17, jloc = p - ky * 17;
            int ii = i0 + ky, jj = jbase + jloc;
            bool valid = (p < 51) && ((unsigned)ii < 64u) && ((unsigned)jj < 64u);
            if (p < 51) ces[p * CESR + m16] = valid ? expf(accc[r]) : 0.f;
        }
    }

    // ---- P1V: kc-outer V = X.Wv (wave owns nt 4wv..4wv+3) ----
    floatx4 acc[4][4];                    // [m][local nt]
    #pragma unroll
    for (int m = 0; m < 4; ++m)
        #pragma unroll
        for (int ln = 0; ln < 4; ++ln)
            acc[m][ln] = (floatx4){0.f, 0.f, 0.f, 0.f};
    {
        const short* bvw = Wvh + (4 * wv) * 4096 + lane * 8;
        #pragma unroll
        for (int kc = 0; kc < 8; ++kc) {
            bf16x8 B0 = *(const bf16x8*)(bvw + 0 * 4096 + kc * 512);
            bf16x8 B1 = *(const bf16x8*)(bvw + 1 * 4096 + kc * 512);
            bf16x8 B2 = *(const bf16x8*)(bvw + 2 * 4096 + kc * 512);
            bf16x8 B3 = *(const bf16x8*)(bvw + 3 * 4096 + kc * 512);
            #pragma unroll
            for (int m = 0; m < 4; ++m) {
                bf16x8 a = *(const bf16x8*)
                    &XA[(m * 16 + m16) * XROW + kc * 32 + quad * 8];
                acc[m][0] = __builtin_amdgcn_mfma_f32_16x16x32_bf16(a, B0, acc[m][0], 0, 0, 0);
                acc[m][1] = __builtin_amdgcn_mfma_f32_16x16x32_bf16(a, B1, acc[m][1], 0, 0, 0);
                acc[m][2] = __builtin_amdgcn_mfma_f32_16x16x32_bf16(a, B2, acc[m][2], 0, 0, 0);
                acc[m][3] = __builtin_amdgcn_mfma_f32_16x16x32_bf16(a, B3, acc[m][3], 0, 0, 0);
            }
        }
    }
    __syncthreads();                      // all XA reads + ces writes done

    // V in place over XA (wave writes its 4 nt columns, all 64 rows)
    #pragma unroll
    for (int m = 0; m < 4; ++m)
        #pragma unroll
        for (int ln = 0; ln < 4; ++ln)
            #pragma unroll
            for (int r = 0; r < 4; ++r)
                XA[(m * 16 + quad * 4 + r) * XROW + (4 * wv + ln) * 16 + m16] =
                    f2bf(acc[m][ln][r]);
    __syncthreads();

    // ---- P2a: invden ----
    if (tid < 128) {
        int op = tid >> 4, g = tid & 15;
        float den = 0.f;
        #pragma unroll
        for (int w = 0; w < 9; ++w) {
            int ky = w / 3, kx = w - ky * 3;
            int row = ky * 17 + 2 * op + kx;
            den = fmaf(rpe_exp[w * 16 + g], ces[row * CESR + g], den);
        }
        invden[op][g] = 1.0f / den;
    }
    __syncthreads();

    // ---- P2b: wcoefs[h][w][op] (queries q=0/1 merged) ----
    for (int it = tid; it < 576; it += 256) {
        int op = it / 72, r = it - op * 72;
        int w = r >> 3, h = r & 7;
        int ky = w / 3, kx = w - ky * 3;
        int row = ky * 17 + 2 * op + kx;
        wcoefs[h][w][op] =
            ces[row * CESR + h]     * rpe_scale[w * 16 + h]     * invden[op][h] +
            ces[row * CESR + 8 + h] * rpe_scale[w * 16 + 8 + h] * invden[op][8 + h];
    }
    __syncthreads();   // ces dead -> pool becomes out_tr

    // ---- P3: stencil on V -> out_tr (thread = (op, 8-feature chunk)) ----
    {
        int op = tid >> 5;                 // 0..7
        int nc = tid & 31;                 // 8-feature chunk
        int h  = nc >> 2;
        float wcv[9];
        #pragma unroll
        for (int w = 0; w < 9; ++w) wcv[w] = wcoefs[h][w][op];

        float o[8];
        #pragma unroll
        for (int j = 0; j < 8; ++j) o[j] = 0.f;
        #pragma unroll
        for (int w = 0; w < 9; ++w) {
            int ky = w / 3, kx = w - ky * 3;
            int row = ky * 17 + 2 * op + kx;
            bf16x8 vv = *(const bf16x8*)&XA[row * XROW + nc * 8];
            #pragma unroll
            for (int j = 0; j < 8; ++j)
                o[j] = fmaf(wcv[w], bf2f(vv[j]), o[j]);   // wcv==0 when OOB
        }
        bf16x8 ob;
        #pragma unroll
        for (int j = 0; j < 8; ++j) ob[j] = f2bf(o[j]);
        *(bf16x8*)&out_tr[op * XROW + nc * 8] = ob;
    }
    __syncthreads();

    // ---- P5: out = out_tr . Wo (wave owns nt 4wv..4wv+3) ----
    {
        floatx4 a5[4];
        #pragma unroll
        for (int ln = 0; ln < 4; ++ln) a5[ln] = (floatx4){0.f, 0.f, 0.f, 0.f};
        int mr = m16 & 7;                 // clamp: rows 8..15 duplicate 0..7
        const short* bp = Bo + (4 * wv) * 4096 + lane * 8;
        #pragma unroll
        for (int kc = 0; kc < 8; ++kc) {
            bf16x8 a  = *(const bf16x8*)&out_tr[mr * XROW + kc * 32 + quad * 8];
            a5[0] = __builtin_amdgcn_mfma_f32_16x16x32_bf16(
                        a, *(const bf16x8*)(bp + 0 * 4096 + kc * 512), a5[0], 0, 0, 0);
            a5[1] = __builtin_amdgcn_mfma_f32_16x16x32_bf16(
                        a, *(const bf16x8*)(bp + 1 * 4096 + kc * 512), a5[1], 0, 0, 0);
            a5[2] = __builtin_amdgcn_mfma_f32_16x16x32_bf16(
                        a, *(const bf16x8*)(bp + 2 * 4096 + kc * 512), a5[2], 0, 0, 0);
            a5[3] = __builtin_amdgcn_mfma_f32_16x16x32_bf16(
                        a, *(const bf16x8*)(bp + 3 * 4096 + kc * 512), a5[3], 0, 0, 0);
        }
        if (quad < 2) {                   // rows 0..7 only
            size_t op0 = (size_t)blk * 8;
            #pragma unroll
            for (int ln = 0; ln < 4; ++ln)
                #pragma unroll
                for (int r = 0; r < 4; ++r)
                    out[(op0 + quad * 4 + r) * 256 + (4 * wv + ln) * 16 + m16] =
                        a5[ln][r];
        }
    }
}

// ---------------------------------------------------------------------------
extern "C" void kernel_launch(void* const* d_in, const int* in_sizes, int n_in,
                              void* d_out, int out_size, void* d_ws, size_t ws_size,
                              hipStream_t stream)
{
    const float* x     = (const float*)d_in[0];
    const float* query = (const float*)d_in[1];
    const float* Wk    = (const float*)d_in[2];
    const float* Wv    = (const float*)d_in[3];
    const float* rpe   = (const float*)d_in[4];
    const float* asw   = (const float*)d_in[5];
    const float* Wo    = (const float*)d_in[6];
    float* out = (float*)d_out;

    float* ws        = (float*)d_ws;
    float* rpe_exp   = ws;                         // 144 f
    float* rpe_scale = ws + 144;                   // 144 f
    short* Bq        = (short*)(ws + 288);         // 4096 bf16
    short* Wvh       = (short*)(ws + 288 + 2048);  // 65536 bf16
    short* Bo        = (short*)(ws + 288 + 2048 + 32768);  // 65536 bf16

    prep_kernel<<<dim3(16), dim3(256), 0, stream>>>(query, Wk, rpe, asw, Wv, Wo,
                                                    rpe_exp, rpe_scale, Bq, Wvh, Bo);
    fused8_kernel<<<dim3(4096), dim3(256), 0, stream>>>(x, rpe_exp, rpe_scale,
                                                        Bq, Wvh, Bo, out);
}